// Round 7
// baseline (54.029 us; speedup 1.0000x reference)
//
#include <hip/hip_runtime.h>

// RecPolicy: per-row bidirectional GRU (H=2) + obs linear + scalar head.
// x: (B,18) f32 = [obs(4), j(7), jd(7)] ; out: (B,7) f32
//
// R7 = R5 numerics + persistent software-pipelined blocks:
//   grid=2048, each block owns 4 tiles of 256 rows. Register prefetch of
//   tile t+1 is issued right after the stage barrier so HBM latency hides
//   under tile t's ~2100-cycle compute. Separate LDS in (18KB) / out (7KB)
//   buffers. Weights prescaled once into d_ws by prep kernel (SGPR via
//   wave-uniform loads).
// Assumes n % 256 == 0 (harness B = 2097152 = 8192 * 256).

using v2f = __attribute__((ext_vector_type(2))) float;

__device__ __forceinline__ float fexp2(float x) { return __builtin_amdgcn_exp2f(x); }
__device__ __forceinline__ float frcp(float x)  { return __builtin_amdgcn_rcpf(x); }

struct Cell {
    v2f wr0, wr1, ur0, ur1, br;   // r gates, prescaled by -log2(e)
    v2f wz0, wz1, uz0, uz1, bz;   // z gates, prescaled by -log2(e)
    v2f wn0, wn1, bni;            // n input part, prescaled by 2*log2(e)
    v2f un0, un1, bnh;            // n hidden part, prescaled by 2*log2(e)
};

// ---- setup kernel: prescale weights once into d_ws ----
// ws layout (floats): [0..31] up Cell, [64..95] dn Cell,
//                     [128..139] w_obs, [140..141] b_obs,
//                     [142..143] w_out, [144] b_out
__global__ void prep_kernel(
    const float* __restrict__ w_ih_up, const float* __restrict__ w_hh_up,
    const float* __restrict__ b_ih_up, const float* __restrict__ b_hh_up,
    const float* __restrict__ w_obs,   const float* __restrict__ b_obs,
    const float* __restrict__ w_ih_dn, const float* __restrict__ w_hh_dn,
    const float* __restrict__ b_ih_dn, const float* __restrict__ b_hh_dn,
    const float* __restrict__ w_out,   const float* __restrict__ b_out,
    float* __restrict__ ws)
{
    if (threadIdx.x != 0 || blockIdx.x != 0) return;
    const float s1 = -1.4426950408889634f;  // -log2(e)
    const float s2 =  2.8853900817779268f;  // 2*log2(e)
    #pragma unroll
    for (int c = 0; c < 2; ++c) {
        const float* wi = c ? w_ih_dn : w_ih_up;
        const float* wh = c ? w_hh_dn : w_hh_up;
        const float* bi = c ? b_ih_dn : b_ih_up;
        const float* bh = c ? b_hh_dn : b_hh_up;
        float* o = ws + c * 64;
        o[0] = s1*wi[0]; o[1] = s1*wi[2];  o[2] = s1*wi[1]; o[3] = s1*wi[3];
        o[4] = s1*wh[0]; o[5] = s1*wh[2];  o[6] = s1*wh[1]; o[7] = s1*wh[3];
        o[8] = s1*(bi[0]+bh[0]); o[9] = s1*(bi[1]+bh[1]);
        o[10] = s1*wi[4]; o[11] = s1*wi[6]; o[12] = s1*wi[5]; o[13] = s1*wi[7];
        o[14] = s1*wh[4]; o[15] = s1*wh[6]; o[16] = s1*wh[5]; o[17] = s1*wh[7];
        o[18] = s1*(bi[2]+bh[2]); o[19] = s1*(bi[3]+bh[3]);
        o[20] = s2*wi[8]; o[21] = s2*wi[10]; o[22] = s2*wi[9]; o[23] = s2*wi[11];
        o[24] = s2*bi[4]; o[25] = s2*bi[5];
        o[26] = s2*wh[8]; o[27] = s2*wh[10]; o[28] = s2*wh[9]; o[29] = s2*wh[11];
        o[30] = s2*bh[4]; o[31] = s2*bh[5];
    }
    #pragma unroll
    for (int i = 0; i < 12; ++i) ws[128 + i] = w_obs[i];
    ws[140] = b_obs[0]; ws[141] = b_obs[1];
    ws[142] = w_out[0]; ws[143] = w_out[1];
    ws[144] = b_out[0];
}

__device__ __forceinline__ void gru(const Cell& c, float x0, float x1, v2f& h) {
    v2f gr = c.br + c.wr0 * x0 + c.wr1 * x1 + c.ur0 * h.x + c.ur1 * h.y;
    v2f gz = c.bz + c.wz0 * x0 + c.wz1 * x1 + c.uz0 * h.x + c.uz1 * h.y;
    v2f r  = (v2f){ frcp(1.0f + fexp2(gr.x)), frcp(1.0f + fexp2(gr.y)) };
    v2f z  = (v2f){ frcp(1.0f + fexp2(gz.x)), frcp(1.0f + fexp2(gz.y)) };
    v2f in = c.bni + c.wn0 * x0 + c.wn1 * x1;
    v2f hn = c.bnh + c.un0 * h.x + c.un1 * h.y;
    v2f a  = in + r * hn;
    v2f n  = (v2f){ 1.0f - 2.0f * frcp(1.0f + fexp2(a.x)),
                    1.0f - 2.0f * frcp(1.0f + fexp2(a.y)) };
    h = n + z * (h - n);   // (1-z)*n + z*h
}

__global__ __launch_bounds__(256) void recpolicy_kernel(
    const float* __restrict__ x, const float* __restrict__ W,
    float* __restrict__ out, int n)
{
    __shared__ float sin_[4608];   // 256 rows x 18 f32 = 18 KiB
    __shared__ float sout[1792];   // 256 rows x 7 f32  =  7 KiB
    const int tid = threadIdx.x;
    const int NT = n >> 8;         // full 256-row tiles (n % 256 == 0)
    const int stride = gridDim.x;

    // wave-uniform prescaled weights (constant indices -> s_load)
    const Cell up = *reinterpret_cast<const Cell*>(W);
    const Cell dn = *reinterpret_cast<const Cell*>(W + 64);

    int t = blockIdx.x;
    if (t >= NT) return;

    const float4* xs = reinterpret_cast<const float4*>(x);
    float4 nx0, nx1, nx2, nx3, nx4;
    {   // prologue: load first tile into regs (coalesced float4)
        size_t b = (size_t)t * 1152;
        nx0 = xs[b + tid];       nx1 = xs[b + 256 + tid];
        nx2 = xs[b + 512 + tid]; nx3 = xs[b + 768 + tid];
        if (tid < 128) nx4 = xs[b + 1024 + tid];
    }

    while (true) {
        {   // stage regs -> LDS (implicit vmcnt wait covers the prefetch)
            float4* d = reinterpret_cast<float4*>(sin_);
            d[tid] = nx0; d[256 + tid] = nx1;
            d[512 + tid] = nx2; d[768 + tid] = nx3;
            if (tid < 128) d[1024 + tid] = nx4;
        }
        __syncthreads();

        const int tn = t + stride;
        if (tn < NT) {   // issue next-tile loads; latency hidden under compute
            size_t b = (size_t)tn * 1152;
            nx0 = xs[b + tid];       nx1 = xs[b + 256 + tid];
            nx2 = xs[b + 512 + tid]; nx3 = xs[b + 768 + tid];
            if (tid < 128) nx4 = xs[b + 1024 + tid];
        }

        // ---- compute row `tid` of this tile ----
        const float* row = sin_ + tid * 18;

        v2f h = (v2f){0.0f, 0.0f};
        v2f hu[7];
        #pragma unroll
        for (int k = 0; k < 7; ++k) {
            const int i = 6 - k;
            gru(up, row[4 + i], row[11 + i], h);
            hu[k] = h;
        }

        {   // obs linear: [obs(4), h(2)] @ w_obs.T + b_obs  (w_obs is (2,6))
            v2f acc = (v2f){W[140], W[141]};
            #pragma unroll
            for (int c = 0; c < 4; ++c)
                acc += (v2f){W[128 + c], W[134 + c]} * row[c];
            acc += (v2f){W[132], W[138]} * h.x;
            acc += (v2f){W[133], W[139]} * h.y;
            h = acc;
        }

        const float wo0 = W[142], wo1 = W[143], bo = W[144];
        #pragma unroll
        for (int k = 0; k < 7; ++k) {
            gru(dn, hu[k].x, hu[k].y, h);
            sout[tid * 7 + k] = fmaf(wo0, h.x, fmaf(wo1, h.y, bo));
        }
        __syncthreads();

        {   // store tile outputs, coalesced float4 (448 float4 per tile)
            const float4* so = reinterpret_cast<const float4*>(sout);
            float4* dst = reinterpret_cast<float4*>(out + (size_t)t * 1792);
            dst[tid] = so[tid];
            if (tid < 192) dst[256 + tid] = so[256 + tid];
        }

        if (tn >= NT) break;
        t = tn;
    }
}

extern "C" void kernel_launch(void* const* d_in, const int* in_sizes, int n_in,
                              void* d_out, int out_size, void* d_ws, size_t ws_size,
                              hipStream_t stream) {
    const float* x       = (const float*)d_in[0];
    const float* w_ih_up = (const float*)d_in[1];
    const float* w_hh_up = (const float*)d_in[2];
    const float* b_ih_up = (const float*)d_in[3];
    const float* b_hh_up = (const float*)d_in[4];
    const float* w_obs   = (const float*)d_in[5];
    const float* b_obs   = (const float*)d_in[6];
    const float* w_ih_dn = (const float*)d_in[7];
    const float* w_hh_dn = (const float*)d_in[8];
    const float* b_ih_dn = (const float*)d_in[9];
    const float* b_hh_dn = (const float*)d_in[10];
    const float* w_out   = (const float*)d_in[11];
    const float* b_out   = (const float*)d_in[12];
    float* out = (float*)d_out;
    float* ws  = (float*)d_ws;

    prep_kernel<<<1, 64, 0, stream>>>(
        w_ih_up, w_hh_up, b_ih_up, b_hh_up, w_obs, b_obs,
        w_ih_dn, w_hh_dn, b_ih_dn, b_hh_dn, w_out, b_out, ws);

    const int n = in_sizes[0] / 18;   // 2097152 -> 8192 full tiles
    const int NT = n >> 8;
    const int grid = NT < 2048 ? NT : 2048;
    recpolicy_kernel<<<grid, 256, 0, stream>>>(x, ws, out, n);
}

// Round 8
// 52.880 us; speedup vs baseline: 1.0217x; 1.0217x over previous
//
#include <hip/hip_runtime.h>

// RecPolicy: per-row bidirectional GRU (H=2) + obs linear + scalar head.
// x: (B,18) f32 = [obs(4), j(7), jd(7)] ; out: (B,7) f32
//
// R8 = R2 structure (1 row/thread, 256-row tile, LDS-staged coalesced I/O)
//    + prep-kernel prescaled weights in d_ws (R5, proven)
//    + paired-rcp activations: rcp(d0*d1) serves both lanes of each
//      sigmoid/tanh pair -> 84 rcp/row -> 42 (trans ops 168 -> 126).
//      Numerics of this trick validated in R3 (absmax unchanged).

using v2f = __attribute__((ext_vector_type(2))) float;

__device__ __forceinline__ float fexp2(float x) { return __builtin_amdgcn_exp2f(x); }
__device__ __forceinline__ float frcp(float x)  { return __builtin_amdgcn_rcpf(x); }

struct Cell {
    v2f wr0, wr1, ur0, ur1, br;   // r gates, prescaled by -log2(e)
    v2f wz0, wz1, uz0, uz1, bz;   // z gates, prescaled by -log2(e)
    v2f wn0, wn1, bni;            // n input part, prescaled by 2*log2(e)
    v2f un0, un1, bnh;            // n hidden part, prescaled by 2*log2(e)
};

// ---- setup kernel: prescale weights once into d_ws ----
// ws layout (floats): [0..31] up Cell, [64..95] dn Cell,
//                     [128..139] w_obs, [140..141] b_obs,
//                     [142..143] w_out, [144] b_out
__global__ void prep_kernel(
    const float* __restrict__ w_ih_up, const float* __restrict__ w_hh_up,
    const float* __restrict__ b_ih_up, const float* __restrict__ b_hh_up,
    const float* __restrict__ w_obs,   const float* __restrict__ b_obs,
    const float* __restrict__ w_ih_dn, const float* __restrict__ w_hh_dn,
    const float* __restrict__ b_ih_dn, const float* __restrict__ b_hh_dn,
    const float* __restrict__ w_out,   const float* __restrict__ b_out,
    float* __restrict__ ws)
{
    if (threadIdx.x != 0 || blockIdx.x != 0) return;
    const float s1 = -1.4426950408889634f;  // -log2(e)
    const float s2 =  2.8853900817779268f;  // 2*log2(e)
    #pragma unroll
    for (int c = 0; c < 2; ++c) {
        const float* wi = c ? w_ih_dn : w_ih_up;
        const float* wh = c ? w_hh_dn : w_hh_up;
        const float* bi = c ? b_ih_dn : b_ih_up;
        const float* bh = c ? b_hh_dn : b_hh_up;
        float* o = ws + c * 64;
        o[0] = s1*wi[0]; o[1] = s1*wi[2];  o[2] = s1*wi[1]; o[3] = s1*wi[3];
        o[4] = s1*wh[0]; o[5] = s1*wh[2];  o[6] = s1*wh[1]; o[7] = s1*wh[3];
        o[8] = s1*(bi[0]+bh[0]); o[9] = s1*(bi[1]+bh[1]);
        o[10] = s1*wi[4]; o[11] = s1*wi[6]; o[12] = s1*wi[5]; o[13] = s1*wi[7];
        o[14] = s1*wh[4]; o[15] = s1*wh[6]; o[16] = s1*wh[5]; o[17] = s1*wh[7];
        o[18] = s1*(bi[2]+bh[2]); o[19] = s1*(bi[3]+bh[3]);
        o[20] = s2*wi[8]; o[21] = s2*wi[10]; o[22] = s2*wi[9]; o[23] = s2*wi[11];
        o[24] = s2*bi[4]; o[25] = s2*bi[5];
        o[26] = s2*wh[8]; o[27] = s2*wh[10]; o[28] = s2*wh[9]; o[29] = s2*wh[11];
        o[30] = s2*bh[4]; o[31] = s2*bh[5];
    }
    #pragma unroll
    for (int i = 0; i < 12; ++i) ws[128 + i] = w_obs[i];
    ws[140] = b_obs[0]; ws[141] = b_obs[1];
    ws[142] = w_out[0]; ws[143] = w_out[1];
    ws[144] = b_out[0];
}

// paired-rcp GRU cell: 6 exp2 + 3 rcp (was 6 + 6)
__device__ __forceinline__ void gru(const Cell& c, float x0, float x1, v2f& h) {
    v2f gr = c.br + c.wr0 * x0 + c.wr1 * x1 + c.ur0 * h.x + c.ur1 * h.y; // -log2e scaled
    v2f gz = c.bz + c.wz0 * x0 + c.wz1 * x1 + c.uz0 * h.x + c.uz1 * h.y; // -log2e scaled
    v2f dr = (v2f){1.0f + fexp2(gr.x), 1.0f + fexp2(gr.y)};
    v2f dz = (v2f){1.0f + fexp2(gz.x), 1.0f + fexp2(gz.y)};
    // r = sigmoid pair via one rcp: inv = 1/(dr0*dr1); r0=inv*dr1, r1=inv*dr0
    float invr = frcp(dr.x * dr.y);
    v2f r = invr * (v2f){dr.y, dr.x};
    v2f gi = c.bni + c.wn0 * x0 + c.wn1 * x1;    // 2log2e scaled
    v2f gh = c.bnh + c.un0 * h.x + c.un1 * h.y;  // 2log2e scaled
    v2f a  = gi + r * gh;
    v2f da = (v2f){1.0f + fexp2(a.x), 1.0f + fexp2(a.y)};
    // tanh pair: m = -2/(da0*da1); n0 = 1 + m*da1, n1 = 1 + m*da0
    float m = -2.0f * frcp(da.x * da.y);
    v2f n = (v2f){fmaf(m, da.y, 1.0f), fmaf(m, da.x, 1.0f)};
    // z pair via one rcp, then blend h = n + z*(h-n)
    float invz = frcp(dz.x * dz.y);
    v2f z = invz * (v2f){dz.y, dz.x};
    h = n + z * (h - n);
}

__global__ __launch_bounds__(256) void recpolicy_kernel(
    const float* __restrict__ x, const float* __restrict__ W,
    float* __restrict__ out, int n)
{
    __shared__ float sin_[4608];   // 256 rows x 18 f32 = 18 KiB
    __shared__ float sout[1792];   // 256 rows x 7 f32  =  7 KiB
    const int tid  = threadIdx.x;
    const int row0 = blockIdx.x * 256;
    const int rows = min(256, n - row0);

    // ---- stage input block into LDS, coalesced float4 ----
    if (rows == 256) {
        const float4* src = reinterpret_cast<const float4*>(x + (size_t)row0 * 18);
        float4* dst = reinterpret_cast<float4*>(sin_);
        #pragma unroll
        for (int i = 0; i < 4; ++i)
            dst[tid + i * 256] = src[tid + i * 256];
        if (tid < 128) dst[tid + 1024] = src[tid + 1024];
    } else {
        for (int idx = tid; idx < rows * 18; idx += 256)
            sin_[idx] = x[(size_t)row0 * 18 + idx];
    }

    // ---- wave-uniform prescaled weights (constant indices -> s_load) ----
    const Cell up = *reinterpret_cast<const Cell*>(W);
    const Cell dn = *reinterpret_cast<const Cell*>(W + 64);

    __syncthreads();

    const float* row = sin_ + tid * 18;

    // ---- up chain: i = 6..0, input (j[i], jd[i]) = row[4+i], row[11+i] ----
    v2f h = (v2f){0.0f, 0.0f};
    v2f hu[7];
    #pragma unroll
    for (int k = 0; k < 7; ++k) {
        const int i = 6 - k;
        gru(up, row[4 + i], row[11 + i], h);
        hu[k] = h;
    }

    // ---- obs linear: [obs(4), h(2)] @ w_obs.T + b_obs  (w_obs is (2,6)) ----
    {
        v2f t = (v2f){W[140], W[141]};
        #pragma unroll
        for (int c = 0; c < 4; ++c)
            t += (v2f){W[128 + c], W[134 + c]} * row[c];
        t += (v2f){W[132], W[138]} * h.x;
        t += (v2f){W[133], W[139]} * h.y;
        h = t;
    }

    // ---- down chain + head, acts staged into LDS ----
    const float wo0 = W[142], wo1 = W[143], bo = W[144];
    #pragma unroll
    for (int k = 0; k < 7; ++k) {
        gru(dn, hu[k].x, hu[k].y, h);
        sout[tid * 7 + k] = fmaf(wo0, h.x, fmaf(wo1, h.y, bo));
    }
    __syncthreads();

    // ---- coalesced float4 store of the block's 256x7 outputs ----
    if (rows == 256) {
        float4* dst = reinterpret_cast<float4*>(out + (size_t)row0 * 7);
        const float4* src = reinterpret_cast<const float4*>(sout);
        dst[tid] = src[tid];
        if (tid < 192) dst[256 + tid] = src[256 + tid];
    } else {
        for (int idx = tid; idx < rows * 7; idx += 256)
            out[(size_t)row0 * 7 + idx] = sout[idx];
    }
}

extern "C" void kernel_launch(void* const* d_in, const int* in_sizes, int n_in,
                              void* d_out, int out_size, void* d_ws, size_t ws_size,
                              hipStream_t stream) {
    const float* x       = (const float*)d_in[0];
    const float* w_ih_up = (const float*)d_in[1];
    const float* w_hh_up = (const float*)d_in[2];
    const float* b_ih_up = (const float*)d_in[3];
    const float* b_hh_up = (const float*)d_in[4];
    const float* w_obs   = (const float*)d_in[5];
    const float* b_obs   = (const float*)d_in[6];
    const float* w_ih_dn = (const float*)d_in[7];
    const float* w_hh_dn = (const float*)d_in[8];
    const float* b_ih_dn = (const float*)d_in[9];
    const float* b_hh_dn = (const float*)d_in[10];
    const float* w_out   = (const float*)d_in[11];
    const float* b_out   = (const float*)d_in[12];
    float* out = (float*)d_out;
    float* ws  = (float*)d_ws;

    prep_kernel<<<1, 64, 0, stream>>>(
        w_ih_up, w_hh_up, b_ih_up, b_hh_up, w_obs, b_obs,
        w_ih_dn, w_hh_dn, b_ih_dn, b_hh_dn, w_out, b_out, ws);

    const int n = in_sizes[0] / 18;
    const int block = 256;
    const int grid = (n + block - 1) / block;
    recpolicy_kernel<<<grid, block, 0, stream>>>(x, ws, out, n);
}